// Round 1
// baseline (632.770 us; speedup 1.0000x reference)
//
#include <hip/hip_runtime.h>
#include <hip/hip_bf16.h>
#include <math.h>

// Problem constants (match reference)
#define BATCH 512
#define NROWS 1024
#define DDIM  256
#define NWAVES 16   // 1024 threads / 64

// One block per batch element. Wave w handles rows n % 16 == w.
// Online (flash-style) softmax: single pass over node_feature, skipping
// masked rows entirely (wave-uniform branch -> halves HBM traffic since
// edge_weight is Bernoulli(0.5)).
__global__ __launch_bounds__(1024, 8) void attn_pool_kernel(
    const float* __restrict__ node,   // [B, N, D]
    const int*   __restrict__ edge,   // [B, N]
    const int*   __restrict__ label,  // [B]
    const float* __restrict__ rel,    // [R, D]
    float*       __restrict__ out)    // [B, D]
{
    const int b    = blockIdx.x;
    const int tid  = threadIdx.x;
    const int lane = tid & 63;
    const int wave = tid >> 6;        // 0..15

    // q fragment: lane holds q[4*lane .. 4*lane+3]
    const int lab = label[b];
    const float4 q = *(const float4*)(rel + (size_t)lab * DDIM + lane * 4);

    const float4* nodeb = (const float4*)(node + (size_t)b * NROWS * DDIM);
    const int*    edgeb = edge + (size_t)b * NROWS;

    float  m = -INFINITY;
    float  l = 0.0f;
    float4 o = make_float4(0.f, 0.f, 0.f, 0.f);

    // 32 iterations of 2 rows (rows n and n+16), stride 32 per wave.
    for (int n = wave; n < NROWS; n += 2 * NWAVES) {
        const int n2 = n + NWAVES;
        const int e1 = edgeb[n];
        const int e2 = edgeb[n2];

        float4 x1, x2;
        // issue both loads before any dependent use (2 outstanding/wave)
        if (e1 == 1) x1 = nodeb[(size_t)n  * (DDIM / 4) + lane];
        if (e2 == 1) x2 = nodeb[(size_t)n2 * (DDIM / 4) + lane];

        if (e1 == 1) {
            float s = x1.x * q.x + x1.y * q.y + x1.z * q.z + x1.w * q.w;
            #pragma unroll
            for (int off = 32; off > 0; off >>= 1) s += __shfl_xor(s, off);
            const float mnew  = fmaxf(m, s);
            const float scale = __expf(m - mnew);   // exp(-inf)=0 on first hit
            const float p     = __expf(s - mnew);
            l = l * scale + p;
            o.x = o.x * scale + p * x1.x;
            o.y = o.y * scale + p * x1.y;
            o.z = o.z * scale + p * x1.z;
            o.w = o.w * scale + p * x1.w;
            m = mnew;
        }
        if (e2 == 1) {
            float s = x2.x * q.x + x2.y * q.y + x2.z * q.z + x2.w * q.w;
            #pragma unroll
            for (int off = 32; off > 0; off >>= 1) s += __shfl_xor(s, off);
            const float mnew  = fmaxf(m, s);
            const float scale = __expf(m - mnew);
            const float p     = __expf(s - mnew);
            l = l * scale + p;
            o.x = o.x * scale + p * x2.x;
            o.y = o.y * scale + p * x2.y;
            o.z = o.z * scale + p * x2.z;
            o.w = o.w * scale + p * x2.w;
            m = mnew;
        }
    }

    // ---- cross-wave merge via LDS ----
    __shared__ float s_m[NWAVES];
    __shared__ float s_l[NWAVES];
    __shared__ float s_o[NWAVES][DDIM];   // 16 KB

    // after butterfly reduce, m/l are uniform across the wave
    if (lane == 0) { s_m[wave] = m; s_l[wave] = l; }
    *(float4*)&s_o[wave][lane * 4] = o;
    __syncthreads();

    if (tid < DDIM) {
        float M = -INFINITY;
        #pragma unroll
        for (int w = 0; w < NWAVES; ++w) M = fmaxf(M, s_m[w]);
        float L = 0.f, acc = 0.f;
        #pragma unroll
        for (int w = 0; w < NWAVES; ++w) {
            const float sc = __expf(s_m[w] - M);
            L   += s_l[w] * sc;
            acc += s_o[w][tid] * sc;
        }
        out[(size_t)b * DDIM + tid] = acc / L;
    }
}

extern "C" void kernel_launch(void* const* d_in, const int* in_sizes, int n_in,
                              void* d_out, int out_size, void* d_ws, size_t ws_size,
                              hipStream_t stream) {
    const float* node  = (const float*)d_in[0];  // [B,N,D] fp32
    const int*   edge  = (const int*)  d_in[1];  // [B,N]
    const int*   label = (const int*)  d_in[2];  // [B]
    const float* rel   = (const float*)d_in[3];  // [R,D]
    float*       out   = (float*)d_out;          // [B,D]

    attn_pool_kernel<<<dim3(BATCH), dim3(1024), 0, stream>>>(node, edge, label, rel, out);
}

// Round 2
// 632.218 us; speedup vs baseline: 1.0009x; 1.0009x over previous
//
#include <hip/hip_runtime.h>
#include <hip/hip_bf16.h>
#include <math.h>

// Problem constants (match reference)
#define BATCH 512
#define NROWS 1024
#define DDIM  256
#define NWAVES 16   // 1024 threads / 16 waves of 64
#define RBATCH 8    // rows processed per inner iteration (MLP/ILP depth)

// One block per batch element b. Wave w owns contiguous rows [64w, 64w+64).
// Lane i tests edge[64w+i] -> __ballot 64-bit active mask; iterate set bits
// in batches of 8: 8 independent float4 loads + 8 independent shuffle-reduce
// chains + one batched online-softmax update. Masked rows are never fetched
// (halves HBM traffic, edge ~ Bernoulli(0.5)).
__global__ __launch_bounds__(1024, 4) void attn_pool_kernel(
    const float* __restrict__ node,   // [B, N, D]
    const int*   __restrict__ edge,   // [B, N]
    const int*   __restrict__ label,  // [B]
    const float* __restrict__ rel,    // [R, D]
    float*       __restrict__ out)    // [B, D]
{
    const int b    = blockIdx.x;
    const int tid  = threadIdx.x;
    const int lane = tid & 63;
    const int wave = tid >> 6;        // 0..15

    // q fragment: lane holds q[4*lane .. 4*lane+3]
    const int lab = label[b];
    const float4 q = *(const float4*)(rel + (size_t)lab * DDIM + lane * 4);

    const float4* nodeb = (const float4*)(node + (size_t)b * NROWS * DDIM);

    // one coalesced edge load per thread; wave w covers rows [64w, 64w+64)
    const int e = edge[(size_t)b * NROWS + tid];
    unsigned long long mask = __ballot(e == 1);   // bit i = row (64w + i) active

    const int rowbase = wave * 64;

    float  m = -INFINITY;
    float  l = 0.0f;
    float4 o = make_float4(0.f, 0.f, 0.f, 0.f);

    while (mask) {
        // ---- extract up to RBATCH set bits (wave-uniform scalar work) ----
        int rows[RBATCH];
        #pragma unroll
        for (int j = 0; j < RBATCH; ++j) {
            if (mask) {
                rows[j] = __ffsll((unsigned long long)mask) - 1;
                mask &= (mask - 1);
            } else {
                rows[j] = -1;
            }
        }

        // ---- issue all loads (8 outstanding float4 per wave) ----
        float4 x[RBATCH];
        #pragma unroll
        for (int j = 0; j < RBATCH; ++j) {
            x[j] = make_float4(0.f, 0.f, 0.f, 0.f);   // masked rows contribute 0
            if (rows[j] >= 0)
                x[j] = nodeb[(size_t)(rowbase + rows[j]) * (DDIM / 4) + lane];
        }

        // ---- partial dots ----
        float s[RBATCH];
        #pragma unroll
        for (int j = 0; j < RBATCH; ++j)
            s[j] = (rows[j] >= 0)
                 ? (x[j].x * q.x + x[j].y * q.y + x[j].z * q.z + x[j].w * q.w)
                 : -INFINITY;   // -inf + -inf = -inf in the reduce: safe, no NaN

        // ---- 8 independent butterfly reductions (latency overlapped) ----
        #pragma unroll
        for (int off = 32; off > 0; off >>= 1) {
            #pragma unroll
            for (int j = 0; j < RBATCH; ++j)
                s[j] += __shfl_xor(s[j], off);
        }

        // ---- batched online-softmax update (one short serial section) ----
        float mnew = m;
        #pragma unroll
        for (int j = 0; j < RBATCH; ++j) mnew = fmaxf(mnew, s[j]);

        const float scale = __expf(m - mnew);   // first iter: exp(-inf)=0
        float p[RBATCH];
        float psum = 0.f;
        #pragma unroll
        for (int j = 0; j < RBATCH; ++j) {
            p[j] = __expf(s[j] - mnew);         // masked j: exp(-inf)=0
            psum += p[j];
        }
        l = l * scale + psum;
        o.x *= scale; o.y *= scale; o.z *= scale; o.w *= scale;
        #pragma unroll
        for (int j = 0; j < RBATCH; ++j) {
            o.x += p[j] * x[j].x;
            o.y += p[j] * x[j].y;
            o.z += p[j] * x[j].z;
            o.w += p[j] * x[j].w;
        }
        m = mnew;
    }

    // ---- cross-wave merge via LDS ----
    __shared__ float s_m[NWAVES];
    __shared__ float s_l[NWAVES];
    __shared__ float s_o[NWAVES][DDIM];   // 16 KB

    if (lane == 0) { s_m[wave] = m; s_l[wave] = l; }   // m,l wave-uniform
    *(float4*)&s_o[wave][lane * 4] = o;
    __syncthreads();

    if (tid < DDIM) {
        float M = -INFINITY;
        #pragma unroll
        for (int w = 0; w < NWAVES; ++w) M = fmaxf(M, s_m[w]);
        float L = 0.f, acc = 0.f;
        #pragma unroll
        for (int w = 0; w < NWAVES; ++w) {
            const float sc = __expf(s_m[w] - M);   // empty wave: exp(-inf)=0
            L   += s_l[w] * sc;
            acc += s_o[w][tid] * sc;
        }
        out[(size_t)b * DDIM + tid] = acc / L;
    }
}

extern "C" void kernel_launch(void* const* d_in, const int* in_sizes, int n_in,
                              void* d_out, int out_size, void* d_ws, size_t ws_size,
                              hipStream_t stream) {
    const float* node  = (const float*)d_in[0];  // [B,N,D] fp32
    const int*   edge  = (const int*)  d_in[1];  // [B,N]
    const int*   label = (const int*)  d_in[2];  // [B]
    const float* rel   = (const float*)d_in[3];  // [R,D]
    float*       out   = (float*)d_out;          // [B,D]

    attn_pool_kernel<<<dim3(BATCH), dim3(1024), 0, stream>>>(node, edge, label, rel, out);
}

// Round 3
// 629.534 us; speedup vs baseline: 1.0051x; 1.0043x over previous
//
#include <hip/hip_runtime.h>
#include <hip/hip_bf16.h>
#include <math.h>

// Problem constants (match reference)
#define BATCH 512
#define NROWS 1024
#define DDIM  256
#define NWAVES 16   // 1024 threads = 16 waves of 64
#define RB 8        // rows per batch (pipeline stage depth)

// Wave w owns contiguous rows [64w, 64w+64); lane i tests edge[64w+i] ->
// one 64-bit __ballot mask per wave. Rows are consumed in batches of 8 with
// SOFTWARE PIPELINING: batch k+1's 8 float4 loads are issued before batch k
// is consumed, keeping ~8 loads continuously in flight per wave (vs the
// drain-refill pattern of R2). Masked rows are never fetched.

__device__ __forceinline__ unsigned extract_issue(
    unsigned long long& mask, const float4* __restrict__ nodeb,
    int rowbase, int lane, float4 x[RB])
{
    unsigned valid = 0;
    #pragma unroll
    for (int j = 0; j < RB; ++j) {
        x[j] = make_float4(0.f, 0.f, 0.f, 0.f);
        if (mask) {                       // wave-uniform branch
            const int r = __ffsll(mask) - 1;
            mask &= (mask - 1);
            valid |= (1u << j);
            x[j] = nodeb[(size_t)(rowbase + r) * (DDIM / 4) + lane];
        }
    }
    return valid;
}

__device__ __forceinline__ void consume(
    unsigned valid, const float4 x[RB], const float4 q,
    float& m, float& l, float4& o)
{
    float s[RB];
    #pragma unroll
    for (int j = 0; j < RB; ++j)
        s[j] = (valid & (1u << j))
             ? fmaf(x[j].x, q.x, fmaf(x[j].y, q.y, fmaf(x[j].z, q.z, x[j].w * q.w)))
             : -INFINITY;                 // stays -inf through the reduce

    #pragma unroll
    for (int off = 32; off > 0; off >>= 1) {
        #pragma unroll
        for (int j = 0; j < RB; ++j)
            s[j] += __shfl_xor(s[j], off);
    }

    float mnew = m;
    #pragma unroll
    for (int j = 0; j < RB; ++j) mnew = fmaxf(mnew, s[j]);   // >=1 finite s

    const float scale = __expf(m - mnew);   // first call: exp(-inf)=0
    float p[RB], psum = 0.f;
    #pragma unroll
    for (int j = 0; j < RB; ++j) { p[j] = __expf(s[j] - mnew); psum += p[j]; }

    l = l * scale + psum;
    o.x *= scale; o.y *= scale; o.z *= scale; o.w *= scale;
    #pragma unroll
    for (int j = 0; j < RB; ++j) {
        o.x = fmaf(p[j], x[j].x, o.x);
        o.y = fmaf(p[j], x[j].y, o.y);
        o.z = fmaf(p[j], x[j].z, o.z);
        o.w = fmaf(p[j], x[j].w, o.w);
    }
    m = mnew;
}

__global__ __launch_bounds__(1024, 4) void attn_pool_kernel(
    const float* __restrict__ node,   // [B, N, D]
    const int*   __restrict__ edge,   // [B, N]
    const int*   __restrict__ label,  // [B]
    const float* __restrict__ rel,    // [R, D]
    float*       __restrict__ out)    // [B, D]
{
    const int b    = blockIdx.x;
    const int tid  = threadIdx.x;
    const int lane = tid & 63;
    const int wave = tid >> 6;

    const int lab = label[b];
    const float4 q = *(const float4*)(rel + (size_t)lab * DDIM + lane * 4);

    const float4* nodeb = (const float4*)(node + (size_t)b * NROWS * DDIM);

    const int e = edge[(size_t)b * NROWS + tid];
    unsigned long long mask = __ballot(e == 1);   // bit i = row (64w+i) active
    const int rowbase = wave * 64;

    float  m = -INFINITY;
    float  l = 0.0f;
    float4 o = make_float4(0.f, 0.f, 0.f, 0.f);

    float4 xA[RB], xB[RB];
    unsigned vA = extract_issue(mask, nodeb, rowbase, lane, xA);
    while (vA) {
        const unsigned vB = extract_issue(mask, nodeb, rowbase, lane, xB);
        consume(vA, xA, q, m, l, o);          // B's loads in flight meanwhile
        if (!vB) break;
        vA = extract_issue(mask, nodeb, rowbase, lane, xA);
        consume(vB, xB, q, m, l, o);          // A's loads in flight meanwhile
    }

    // ---- cross-wave merge via LDS ----
    __shared__ float s_m[NWAVES];
    __shared__ float s_l[NWAVES];
    __shared__ float s_o[NWAVES][DDIM];   // 16 KB

    if (lane == 0) { s_m[wave] = m; s_l[wave] = l; }   // wave-uniform after reduce
    *(float4*)&s_o[wave][lane * 4] = o;
    __syncthreads();

    if (tid < DDIM) {
        float M = -INFINITY;
        #pragma unroll
        for (int w = 0; w < NWAVES; ++w) M = fmaxf(M, s_m[w]);
        float L = 0.f, acc = 0.f;
        #pragma unroll
        for (int w = 0; w < NWAVES; ++w) {
            const float sc = __expf(s_m[w] - M);   // empty wave: exp(-inf)=0
            L   += s_l[w] * sc;
            acc += s_o[w][tid] * sc;
        }
        out[(size_t)b * DDIM + tid] = acc / L;
    }
}

extern "C" void kernel_launch(void* const* d_in, const int* in_sizes, int n_in,
                              void* d_out, int out_size, void* d_ws, size_t ws_size,
                              hipStream_t stream) {
    const float* node  = (const float*)d_in[0];  // [B,N,D] fp32
    const int*   edge  = (const int*)  d_in[1];  // [B,N]
    const int*   label = (const int*)  d_in[2];  // [B]
    const float* rel   = (const float*)d_in[3];  // [R,D]
    float*       out   = (float*)d_out;          // [B,D]

    attn_pool_kernel<<<dim3(BATCH), dim3(1024), 0, stream>>>(node, edge, label, rel, out);
}